// Round 15
// baseline (97.450 us; speedup 1.0000x reference)
//
#include <hip/hip_runtime.h>

#define CAP  64      // max neighbors stored per node (Poisson(16) tail @64 ~ 1e-20)
#define BN   64      // nodes per bucket (pow2); bucket = d >> 6
#define NBMAX 1024   // LDS histogram capacity (nb = ceil(N/64) = 782)
#define ECAP 2048    // per-bucket edge record capacity (mean 1024, +32 sigma)
#define P1E  4096    // edges per k_part block

typedef unsigned int uint;
typedef unsigned short ushort;
typedef __attribute__((ext_vector_type(8))) short short8;   // 8 bf16 = 4 VGPR
typedef __attribute__((ext_vector_type(4))) float f32x4;    // MFMA accumulator

__device__ inline ushort f2bf(float f) {
    uint u = __float_as_uint(f);
    return (ushort)((u + 0x7fffu + ((u >> 16) & 1u)) >> 16);   // RNE
}
__device__ inline uint packbf2(float lo, float hi) {
    return (uint)f2bf(lo) | ((uint)f2bf(hi) << 16);
}
__device__ inline void unpackbf2(uint u, float& lo, float& hi) {
    lo = __uint_as_float(u << 16);
    hi = __uint_as_float(u & 0xffff0000u);
}

// unpack 2 uint4 (16 ushort idx) into s[16]
#define UNPACK16(s, v0, v1)                                        \
    {   uint _w[8] = {v0.x, v0.y, v0.z, v0.w, v1.x, v1.y, v1.z, v1.w}; \
        _Pragma("unroll")                                          \
        for (int _u = 0; _u < 8; _u++) {                           \
            s[2*_u]   = _w[_u] & 0xffff;                           \
            s[2*_u+1] = _w[_u] >> 16;                              \
        } }

// one 16-neighbor gather batch: h loads + FMA into acc[8] (CH channels, lane*8 offset)
#define GATHER16(acc, s, w, Hb, CH, lane)                          \
    {   uint4 _h[16];                                              \
        _Pragma("unroll")                                          \
        for (int _u = 0; _u < 16; _u++)                            \
            _h[_u] = *(const uint4*)((Hb) + (size_t)(s)[_u] * (CH) + (lane) * 8); \
        _Pragma("unroll")                                          \
        for (int _u = 0; _u < 16; _u++) {                          \
            float _f0, _f1;                                        \
            unpackbf2(_h[_u].x, _f0, _f1); acc[0] += _f0 * (w)[_u]; acc[1] += _f1 * (w)[_u]; \
            unpackbf2(_h[_u].y, _f0, _f1); acc[2] += _f0 * (w)[_u]; acc[3] += _f1 * (w)[_u]; \
            unpackbf2(_h[_u].z, _f0, _f1); acc[4] += _f0 * (w)[_u]; acc[5] += _f1 * (w)[_u]; \
            unpackbf2(_h[_u].w, _f0, _f1); acc[6] += _f0 * (w)[_u]; acc[7] += _f1 * (w)[_u]; \
        } }

// ---- init: zero gtail + pack W1/W2 into B-fragment bf16 layout ----
__global__ __launch_bounds__(256) void k_init(const float* __restrict__ W1,
                                              const float* __restrict__ W2,
                                              ushort* __restrict__ W1t,
                                              ushort* __restrict__ W2t,
                                              int* __restrict__ gtail) {
    int i = blockIdx.x * 256 + threadIdx.x;
    if (i < NBMAX) gtail[i] = 0;
    if (i < 4 * 128 * 32) {
        int kt = i >> 12;
        int nn = (i >> 5) & 127;
        int ko = i & 31;
        W1t[i] = f2bf(W1[(size_t)(kt * 32 + ko) * 128 + nn]);
    }
    int j = i - 4 * 128 * 32;
    if (j >= 0 && j < 4 * 64 * 32) {
        int kt = j >> 11;
        int nn = (j >> 5) & 63;
        int ko = j & 31;
        W2t[j] = f2bf(W2[(size_t)(kt * 32 + ko) * 64 + nn]);
    }
}

// ---- pass 1: radix-partition edges into per-bucket record arrays ----
__global__ __launch_bounds__(256) void k_part(const int* __restrict__ esrc,
                                              const int* __restrict__ edst,
                                              int E, int nb,
                                              int* __restrict__ gtail,
                                              uint* __restrict__ ebuf) {
    __shared__ int hist[NBMAX];
    int base = blockIdx.x * P1E;
    for (int i = threadIdx.x; i < nb; i += 256) hist[i] = 0;
    __syncthreads();

    int d[16], s[16];
#pragma unroll
    for (int u = 0; u < 4; u++) {
        int e = base + (u * 256 + threadIdx.x) * 4;
        int4 dd, ss;
        if (e + 3 < E) {
            dd = *(const int4*)(edst + e);
            ss = *(const int4*)(esrc + e);
        } else {
            dd.x = (e     < E) ? edst[e]     : -1;
            dd.y = (e + 1 < E) ? edst[e + 1] : -1;
            dd.z = (e + 2 < E) ? edst[e + 2] : -1;
            dd.w = (e + 3 < E) ? edst[e + 3] : -1;
            ss.x = (e     < E) ? esrc[e]     : 0;
            ss.y = (e + 1 < E) ? esrc[e + 1] : 0;
            ss.z = (e + 2 < E) ? esrc[e + 2] : 0;
            ss.w = (e + 3 < E) ? esrc[e + 3] : 0;
        }
        d[4*u] = dd.x; d[4*u+1] = dd.y; d[4*u+2] = dd.z; d[4*u+3] = dd.w;
        s[4*u] = ss.x; s[4*u+1] = ss.y; s[4*u+2] = ss.z; s[4*u+3] = ss.w;
    }
#pragma unroll
    for (int u = 0; u < 16; u++)
        if (d[u] >= 0) atomicAdd(&hist[d[u] >> 6], 1);
    __syncthreads();

    for (int i = threadIdx.x; i < nb; i += 256) {
        int h = hist[i];
        hist[i] = (h > 0) ? atomicAdd(&gtail[i], h) : 0;
    }
    __syncthreads();

#pragma unroll
    for (int u = 0; u < 16; u++) {
        if (d[u] >= 0) {
            int b = d[u] >> 6;
            int slot = atomicAdd(&hist[b], 1);
            if (slot < ECAP)
                ebuf[(size_t)b * ECAP + slot] =
                    ((uint)(d[u] & (BN - 1)) << 16) | (uint)s[u];
        }
    }
}

// ---- pass 2: per-bucket LDS scatter -> full-line colbuf + cnt/dinv ----
__global__ __launch_bounds__(256) void k_csr(const uint* __restrict__ ebuf,
                                             const int* __restrict__ gtail,
                                             int n,
                                             ushort* __restrict__ colbuf,
                                             int* __restrict__ cnt,
                                             float* __restrict__ dinv) {
    __shared__ ushort cb[BN * CAP];   // 8KB
    __shared__ int cl[BN];
    int b = blockIdx.x;
    int ne = gtail[b];
    if (ne > ECAP) ne = ECAP;
    for (int i = threadIdx.x; i < BN; i += 256) cl[i] = 0;
    __syncthreads();

    const uint* eb = ebuf + (size_t)b * ECAP;
    for (int i = threadIdx.x * 4; i < ne; i += 1024) {
        uint4 pr4 = *(const uint4*)(eb + i);   // masked per element; row cap ECAP
        uint prs[4] = {pr4.x, pr4.y, pr4.z, pr4.w};
#pragma unroll
        for (int k = 0; k < 4; k++) {
            if (i + k < ne) {
                int dloc = prs[k] >> 16;
                int p = atomicAdd(&cl[dloc], 1);
                if (p < CAP) cb[dloc * CAP + p] = (ushort)(prs[k] & 0xffffu);
            }
        }
    }
    __syncthreads();

    int node0 = b * BN;
    for (int i = threadIdx.x; i < BN * CAP / 8; i += 256) {
        int node = node0 + i / (CAP / 8);
        if (node < n)
            ((uint4*)&colbuf[(size_t)node0 * CAP])[i] = ((const uint4*)cb)[i];
    }
    for (int i = threadIdx.x; i < BN; i += 256) {
        int node = node0 + i;
        if (node < n) {
            int c = cl[i];
            dinv[node] = rsqrtf((float)c + 1.0f);
            cnt[node] = (c > CAP) ? CAP : c;
        }
    }
}

// ---- MFMA GEMM layer 1: hW1b[n,128](bf16) = X[n,128](f32) @ W1 ----
__global__ __launch_bounds__(256) void k_mgemm1(const float* __restrict__ Xf,
                                                const ushort* __restrict__ Wt,
                                                ushort* __restrict__ Yb, int n) {
    __shared__ ushort Ws[4 * 128 * 32];
    for (int idx = threadIdx.x; idx < 4 * 128 * 32 / 8; idx += 256)
        ((uint4*)Ws)[idx] = ((const uint4*)Wt)[idx];
    __syncthreads();

    int wid  = threadIdx.x >> 6;
    int l    = threadIdx.x & 63;
    int mrow = l & 15;
    int kgrp = l >> 4;
    int row16 = (blockIdx.x * 4 + wid) * 16;
    int r  = row16 + mrow;
    int rc = (r < n) ? r : (n - 1);

    f32x4 acc[8];
#pragma unroll
    for (int t = 0; t < 8; t++) acc[t] = (f32x4){0.f, 0.f, 0.f, 0.f};

#pragma unroll
    for (int kt = 0; kt < 4; kt++) {
        const float* xp = &Xf[(size_t)rc * 128 + kt * 32 + kgrp * 8];
        float4 x0 = *(const float4*)xp;
        float4 x1 = *(const float4*)(xp + 4);
        short8 a;
        a[0] = (short)f2bf(x0.x); a[1] = (short)f2bf(x0.y);
        a[2] = (short)f2bf(x0.z); a[3] = (short)f2bf(x0.w);
        a[4] = (short)f2bf(x1.x); a[5] = (short)f2bf(x1.y);
        a[6] = (short)f2bf(x1.z); a[7] = (short)f2bf(x1.w);
#pragma unroll
        for (int t = 0; t < 8; t++) {
            short8 b = *(const short8*)&Ws[((kt * 128) + t * 16 + mrow) * 32 + kgrp * 8];
            acc[t] = __builtin_amdgcn_mfma_f32_16x16x32_bf16(a, b, acc[t], 0, 0, 0);
        }
    }

    int orow = row16 + kgrp * 4;
#pragma unroll
    for (int t = 0; t < 8; t++) {
#pragma unroll
        for (int q = 0; q < 4; q++) {
            int rr = orow + q;
            if (rr < n) Yb[(size_t)rr * 128 + t * 16 + mrow] = f2bf(acc[t][q]);
        }
    }
}

// ---- MFMA GEMM layer 2: hW2b[n,64](bf16) = x1b[n,128](bf16) @ W2 ----
__global__ __launch_bounds__(256) void k_mgemm2(const ushort* __restrict__ Xh,
                                                const ushort* __restrict__ Wt,
                                                ushort* __restrict__ Yb, int n) {
    __shared__ ushort Ws[4 * 64 * 32];   // 16KB
    for (int idx = threadIdx.x; idx < 4 * 64 * 32 / 8; idx += 256)
        ((uint4*)Ws)[idx] = ((const uint4*)Wt)[idx];
    __syncthreads();

    int wid  = threadIdx.x >> 6;
    int l    = threadIdx.x & 63;
    int mrow = l & 15;
    int kgrp = l >> 4;
    int row16 = (blockIdx.x * 4 + wid) * 16;
    int r  = row16 + mrow;
    int rc = (r < n) ? r : (n - 1);

    f32x4 acc[4];
#pragma unroll
    for (int t = 0; t < 4; t++) acc[t] = (f32x4){0.f, 0.f, 0.f, 0.f};

#pragma unroll
    for (int kt = 0; kt < 4; kt++) {
        short8 a = *(const short8*)&Xh[(size_t)rc * 128 + kt * 32 + kgrp * 8];
#pragma unroll
        for (int t = 0; t < 4; t++) {
            short8 b = *(const short8*)&Ws[((kt * 64) + t * 16 + mrow) * 32 + kgrp * 8];
            acc[t] = __builtin_amdgcn_mfma_f32_16x16x32_bf16(a, b, acc[t], 0, 0, 0);
        }
    }

    int orow = row16 + kgrp * 4;
#pragma unroll
    for (int t = 0; t < 4; t++) {
#pragma unroll
        for (int q = 0; q < 4; q++) {
            int rr = orow + q;
            if (rr < n) Yb[(size_t)rr * 64 + t * 16 + mrow] = f2bf(acc[t][q]);
        }
    }
}

// ---- layer-1 aggregate: 2 nodes per 16-lane group, node-1 rows prefetched ----
__global__ __launch_bounds__(256) void k_agg1(const ushort* __restrict__ Hb,
                                              const int* __restrict__ cntc,
                                              const ushort* __restrict__ colbuf,
                                              const float* __restrict__ dinv,
                                              const float* __restrict__ b1,
                                              ushort* __restrict__ x1b, int n) {
    const int CH = 128, LPG = 16;
    int t    = blockIdx.x * 256 + threadIdx.x;
    int g    = t / LPG;
    int lane = t % LPG;
    int g0   = g * 2;
    if (g0 >= n) return;
    int g1   = g0 + 1;
    bool has1 = (g1 < n);
    int gc1  = has1 ? g1 : g0;

    // prologue: metadata + index rows + self rows for BOTH nodes
    float di0 = dinv[g0], di1 = dinv[gc1];
    int c0 = cntc[g0];  if (c0 > CAP) c0 = CAP;
    int c1 = has1 ? cntc[g1] : 0;  if (c1 > CAP) c1 = CAP;
    const ushort* cb0 = colbuf + (size_t)g0  * CAP;
    const ushort* cb1 = colbuf + (size_t)gc1 * CAP;
    uint4 iva0 = *(const uint4*)(cb0);
    uint4 iva1 = *(const uint4*)(cb0 + 8);
    uint4 ivb0 = *(const uint4*)(cb1);
    uint4 ivb1 = *(const uint4*)(cb1 + 8);
    uint4 self0 = *(const uint4*)(Hb + (size_t)g0  * CH + lane * 8);
    uint4 self1 = *(const uint4*)(Hb + (size_t)gc1 * CH + lane * 8);
    float4 bbl = *(const float4*)&b1[lane * 8];
    float4 bbh = *(const float4*)&b1[lane * 8 + 4];
    float bb[8] = {bbl.x, bbl.y, bbl.z, bbl.w, bbh.x, bbh.y, bbh.z, bbh.w};

    // ---------------- node 0 ----------------
    float acc[8];
#pragma unroll
    for (int k = 0; k < 8; k++) acc[k] = 0.f;
    {
        int s[16];
        UNPACK16(s, iva0, iva1);
#pragma unroll
        for (int u = 1; u < 16; u++) if (u >= c0) s[u] = s[0];
        float w[16];
#pragma unroll
        for (int u = 0; u < 16; u++) w[u] = (u < c0) ? dinv[s[u]] : 0.f;
        if (c0 > 0) GATHER16(acc, s, w, Hb, CH, lane);
        for (int j = 16; j < c0; j += 16) {
            uint4 v0 = *(const uint4*)(cb0 + j);
            uint4 v1 = *(const uint4*)(cb0 + j + 8);
            UNPACK16(s, v0, v1);
#pragma unroll
            for (int u = 1; u < 16; u++) if (j + u >= c0) s[u] = s[0];
#pragma unroll
            for (int u = 0; u < 16; u++) w[u] = (j + u < c0) ? dinv[s[u]] : 0.f;
            GATHER16(acc, s, w, Hb, CH, lane);
        }
    }
    {
        float sf[8];
        unpackbf2(self0.x, sf[0], sf[1]);
        unpackbf2(self0.y, sf[2], sf[3]);
        unpackbf2(self0.z, sf[4], sf[5]);
        unpackbf2(self0.w, sf[6], sf[7]);
        float xv[8];
#pragma unroll
        for (int k = 0; k < 8; k++)
            xv[k] = fmaxf((acc[k] + di0 * sf[k]) * di0 + bb[k], 0.f);
        uint up[4] = { packbf2(xv[0], xv[1]), packbf2(xv[2], xv[3]),
                       packbf2(xv[4], xv[5]), packbf2(xv[6], xv[7]) };
        *(uint4*)&x1b[(size_t)g0 * CH + lane * 8] = *(uint4*)up;
    }

    // ---------------- node 1 ----------------
    if (!has1) return;
#pragma unroll
    for (int k = 0; k < 8; k++) acc[k] = 0.f;
    {
        int s[16];
        UNPACK16(s, ivb0, ivb1);
#pragma unroll
        for (int u = 1; u < 16; u++) if (u >= c1) s[u] = s[0];
        float w[16];
#pragma unroll
        for (int u = 0; u < 16; u++) w[u] = (u < c1) ? dinv[s[u]] : 0.f;
        if (c1 > 0) GATHER16(acc, s, w, Hb, CH, lane);
        for (int j = 16; j < c1; j += 16) {
            uint4 v0 = *(const uint4*)(cb1 + j);
            uint4 v1 = *(const uint4*)(cb1 + j + 8);
            UNPACK16(s, v0, v1);
#pragma unroll
            for (int u = 1; u < 16; u++) if (j + u >= c1) s[u] = s[0];
#pragma unroll
            for (int u = 0; u < 16; u++) w[u] = (j + u < c1) ? dinv[s[u]] : 0.f;
            GATHER16(acc, s, w, Hb, CH, lane);
        }
    }
    {
        float sf[8];
        unpackbf2(self1.x, sf[0], sf[1]);
        unpackbf2(self1.y, sf[2], sf[3]);
        unpackbf2(self1.z, sf[4], sf[5]);
        unpackbf2(self1.w, sf[6], sf[7]);
        float xv[8];
#pragma unroll
        for (int k = 0; k < 8; k++)
            xv[k] = fmaxf((acc[k] + di1 * sf[k]) * di1 + bb[k], 0.f);
        uint up[4] = { packbf2(xv[0], xv[1]), packbf2(xv[2], xv[3]),
                       packbf2(xv[4], xv[5]), packbf2(xv[6], xv[7]) };
        *(uint4*)&x1b[(size_t)g1 * CH + lane * 8] = *(uint4*)up;
    }
}

// ---- layer-2 aggregate: 2 nodes per 8-lane group, node-1 rows prefetched ----
__global__ __launch_bounds__(256) void k_agg2(const ushort* __restrict__ Hb,
                                              const int* __restrict__ cntc,
                                              const ushort* __restrict__ colbuf,
                                              const float* __restrict__ dinv,
                                              const float* __restrict__ b2,
                                              float* __restrict__ out, int n) {
    const int CH = 64, LPG = 8;
    int t    = blockIdx.x * 256 + threadIdx.x;
    int g    = t / LPG;
    int lane = t % LPG;
    int g0   = g * 2;
    if (g0 >= n) return;
    int g1   = g0 + 1;
    bool has1 = (g1 < n);
    int gc1  = has1 ? g1 : g0;

    float di0 = dinv[g0], di1 = dinv[gc1];
    int c0 = cntc[g0];  if (c0 > CAP) c0 = CAP;
    int c1 = has1 ? cntc[g1] : 0;  if (c1 > CAP) c1 = CAP;
    const ushort* cb0 = colbuf + (size_t)g0  * CAP;
    const ushort* cb1 = colbuf + (size_t)gc1 * CAP;
    uint4 iva0 = *(const uint4*)(cb0);
    uint4 iva1 = *(const uint4*)(cb0 + 8);
    uint4 ivb0 = *(const uint4*)(cb1);
    uint4 ivb1 = *(const uint4*)(cb1 + 8);
    uint4 self0 = *(const uint4*)(Hb + (size_t)g0  * CH + lane * 8);
    uint4 self1 = *(const uint4*)(Hb + (size_t)gc1 * CH + lane * 8);
    float4 bbl = *(const float4*)&b2[lane * 8];
    float4 bbh = *(const float4*)&b2[lane * 8 + 4];
    float bb[8] = {bbl.x, bbl.y, bbl.z, bbl.w, bbh.x, bbh.y, bbh.z, bbh.w};

    // ---------------- node 0 ----------------
    float acc[8];
#pragma unroll
    for (int k = 0; k < 8; k++) acc[k] = 0.f;
    {
        int s[16];
        UNPACK16(s, iva0, iva1);
#pragma unroll
        for (int u = 1; u < 16; u++) if (u >= c0) s[u] = s[0];
        float w[16];
#pragma unroll
        for (int u = 0; u < 16; u++) w[u] = (u < c0) ? dinv[s[u]] : 0.f;
        if (c0 > 0) GATHER16(acc, s, w, Hb, CH, lane);
        for (int j = 16; j < c0; j += 16) {
            uint4 v0 = *(const uint4*)(cb0 + j);
            uint4 v1 = *(const uint4*)(cb0 + j + 8);
            UNPACK16(s, v0, v1);
#pragma unroll
            for (int u = 1; u < 16; u++) if (j + u >= c0) s[u] = s[0];
#pragma unroll
            for (int u = 0; u < 16; u++) w[u] = (j + u < c0) ? dinv[s[u]] : 0.f;
            GATHER16(acc, s, w, Hb, CH, lane);
        }
    }
    {
        float sf[8];
        unpackbf2(self0.x, sf[0], sf[1]);
        unpackbf2(self0.y, sf[2], sf[3]);
        unpackbf2(self0.z, sf[4], sf[5]);
        unpackbf2(self0.w, sf[6], sf[7]);
        float o[8];
#pragma unroll
        for (int k = 0; k < 8; k++)
            o[k] = (acc[k] + di0 * sf[k]) * di0 + bb[k];
        float* dst = out + (size_t)g0 * CH + lane * 8;
        *(float4*)dst       = make_float4(o[0], o[1], o[2], o[3]);
        *(float4*)(dst + 4) = make_float4(o[4], o[5], o[6], o[7]);
    }

    // ---------------- node 1 ----------------
    if (!has1) return;
#pragma unroll
    for (int k = 0; k < 8; k++) acc[k] = 0.f;
    {
        int s[16];
        UNPACK16(s, ivb0, ivb1);
#pragma unroll
        for (int u = 1; u < 16; u++) if (u >= c1) s[u] = s[0];
        float w[16];
#pragma unroll
        for (int u = 0; u < 16; u++) w[u] = (u < c1) ? dinv[s[u]] : 0.f;
        if (c1 > 0) GATHER16(acc, s, w, Hb, CH, lane);
        for (int j = 16; j < c1; j += 16) {
            uint4 v0 = *(const uint4*)(cb1 + j);
            uint4 v1 = *(const uint4*)(cb1 + j + 8);
            UNPACK16(s, v0, v1);
#pragma unroll
            for (int u = 1; u < 16; u++) if (j + u >= c1) s[u] = s[0];
#pragma unroll
            for (int u = 0; u < 16; u++) w[u] = (j + u < c1) ? dinv[s[u]] : 0.f;
            GATHER16(acc, s, w, Hb, CH, lane);
        }
    }
    {
        float sf[8];
        unpackbf2(self1.x, sf[0], sf[1]);
        unpackbf2(self1.y, sf[2], sf[3]);
        unpackbf2(self1.z, sf[4], sf[5]);
        unpackbf2(self1.w, sf[6], sf[7]);
        float o[8];
#pragma unroll
        for (int k = 0; k < 8; k++)
            o[k] = (acc[k] + di1 * sf[k]) * di1 + bb[k];
        float* dst = out + (size_t)g1 * CH + lane * 8;
        *(float4*)dst       = make_float4(o[0], o[1], o[2], o[3]);
        *(float4*)(dst + 4) = make_float4(o[4], o[5], o[6], o[7]);
    }
}

extern "C" void kernel_launch(void* const* d_in, const int* in_sizes, int n_in,
                              void* d_out, int out_size, void* d_ws, size_t ws_size,
                              hipStream_t stream) {
    const float* x  = (const float*)d_in[0];
    const int*   ei = (const int*)d_in[1];
    const float* W1 = (const float*)d_in[2];
    const float* b1 = (const float*)d_in[3];
    const float* W2 = (const float*)d_in[4];
    const float* b2 = (const float*)d_in[5];
    float* out = (float*)d_out;

    int N = in_sizes[0] / 128;
    int E = in_sizes[1] / 2;
    const int* esrc = ei;       // edge_index[0]
    const int* edst = ei + E;   // edge_index[1]

    int nb = (N + BN - 1) / BN;   // 782 buckets

    char* ws = (char*)d_ws;
    size_t off = 0;
    auto alloc = [&](size_t bytes) -> void* {
        off = (off + 255) & ~(size_t)255;
        void* p = ws + off;
        off += bytes;
        return p;
    };
    int*    gtail   = (int*)   alloc((size_t)NBMAX * 4);          // 4KB
    int*    cnt     = (int*)   alloc((size_t)N * 4);
    float*  dinv    = (float*) alloc((size_t)N * 4);
    uint*   ebuf    = (uint*)  alloc((size_t)nb * ECAP * 4);      // 6.4MB
    ushort* colbuf  = (ushort*)alloc((size_t)nb * BN * CAP * 2 + 256);  // 6.4MB
    ushort* hW1b    = (ushort*)alloc((size_t)N * 128 * 2);        // 12.8MB
    ushort* x1b     = (ushort*)alloc((size_t)N * 128 * 2);        // 12.8MB
    ushort* hW2b    = (ushort*)alloc((size_t)N * 64 * 2);         // 6.4MB
    ushort* W1t     = (ushort*)alloc((size_t)4 * 128 * 32 * 2);   // 32KB
    ushort* W2t     = (ushort*)alloc((size_t)4 * 64 * 32 * 2);    // 16KB

    k_init<<<96, 256, 0, stream>>>(W1, W2, W1t, W2t, gtail);

    int nbP1 = (E + P1E - 1) / P1E;
    k_part<<<nbP1, 256, 0, stream>>>(esrc, edst, E, nb, gtail, ebuf);
    k_mgemm1<<<(N + 63) / 64, 256, 0, stream>>>(x, W1t, hW1b, N);
    k_csr<<<nb, 256, 0, stream>>>(ebuf, gtail, N, colbuf, cnt, dinv);

    int ng1 = (N + 1) / 2;   // node pairs
    k_agg1<<<((size_t)ng1 * 16 + 255) / 256, 256, 0, stream>>>(
        hW1b, cnt, colbuf, dinv, b1, x1b, N);

    k_mgemm2<<<(N + 63) / 64, 256, 0, stream>>>(x1b, W2t, hW2b, N);

    k_agg2<<<((size_t)ng1 * 8 + 255) / 256, 256, 0, stream>>>(
        hW2b, cnt, colbuf, dinv, b2, out, N);
}

// Round 16
// 91.601 us; speedup vs baseline: 1.0639x; 1.0639x over previous
//
#include <hip/hip_runtime.h>

#define CAP  64      // max neighbors stored per node (Poisson(16) tail @64 ~ 1e-20)
#define BN   64      // nodes per bucket (pow2); bucket = d >> 6
#define NBMAX 1024   // LDS histogram capacity (nb = ceil(N/64) = 782)
#define ECAP 2048    // per-bucket edge record capacity (mean 1024, +32 sigma)
#define P1E  4096    // edges per k_part block

typedef unsigned int uint;
typedef unsigned short ushort;
typedef __attribute__((ext_vector_type(8))) short short8;   // 8 bf16 = 4 VGPR
typedef __attribute__((ext_vector_type(4))) float f32x4;    // MFMA accumulator

__device__ inline ushort f2bf(float f) {
    uint u = __float_as_uint(f);
    return (ushort)((u + 0x7fffu + ((u >> 16) & 1u)) >> 16);   // RNE
}
__device__ inline uint packbf2(float lo, float hi) {
    return (uint)f2bf(lo) | ((uint)f2bf(hi) << 16);
}
__device__ inline void unpackbf2(uint u, float& lo, float& hi) {
    lo = __uint_as_float(u << 16);
    hi = __uint_as_float(u & 0xffff0000u);
}

// ---- init: zero gtail + pack W1/W2 into B-fragment bf16 layout ----
__global__ __launch_bounds__(256) void k_init(const float* __restrict__ W1,
                                              const float* __restrict__ W2,
                                              ushort* __restrict__ W1t,
                                              ushort* __restrict__ W2t,
                                              int* __restrict__ gtail) {
    int i = blockIdx.x * 256 + threadIdx.x;
    if (i < NBMAX) gtail[i] = 0;
    if (i < 4 * 128 * 32) {
        int kt = i >> 12;
        int nn = (i >> 5) & 127;
        int ko = i & 31;
        W1t[i] = f2bf(W1[(size_t)(kt * 32 + ko) * 128 + nn]);
    }
    int j = i - 4 * 128 * 32;
    if (j >= 0 && j < 4 * 64 * 32) {
        int kt = j >> 11;
        int nn = (j >> 5) & 63;
        int ko = j & 31;
        W2t[j] = f2bf(W2[(size_t)(kt * 32 + ko) * 64 + nn]);
    }
}

// ---- pass 1: radix-partition edges into per-bucket record arrays ----
__global__ __launch_bounds__(256) void k_part(const int* __restrict__ esrc,
                                              const int* __restrict__ edst,
                                              int E, int nb,
                                              int* __restrict__ gtail,
                                              uint* __restrict__ ebuf) {
    __shared__ int hist[NBMAX];
    int base = blockIdx.x * P1E;
    for (int i = threadIdx.x; i < nb; i += 256) hist[i] = 0;
    __syncthreads();

    int d[16], s[16];
#pragma unroll
    for (int u = 0; u < 4; u++) {
        int e = base + (u * 256 + threadIdx.x) * 4;
        int4 dd, ss;
        if (e + 3 < E) {
            dd = *(const int4*)(edst + e);
            ss = *(const int4*)(esrc + e);
        } else {
            dd.x = (e     < E) ? edst[e]     : -1;
            dd.y = (e + 1 < E) ? edst[e + 1] : -1;
            dd.z = (e + 2 < E) ? edst[e + 2] : -1;
            dd.w = (e + 3 < E) ? edst[e + 3] : -1;
            ss.x = (e     < E) ? esrc[e]     : 0;
            ss.y = (e + 1 < E) ? esrc[e + 1] : 0;
            ss.z = (e + 2 < E) ? esrc[e + 2] : 0;
            ss.w = (e + 3 < E) ? esrc[e + 3] : 0;
        }
        d[4*u] = dd.x; d[4*u+1] = dd.y; d[4*u+2] = dd.z; d[4*u+3] = dd.w;
        s[4*u] = ss.x; s[4*u+1] = ss.y; s[4*u+2] = ss.z; s[4*u+3] = ss.w;
    }
#pragma unroll
    for (int u = 0; u < 16; u++)
        if (d[u] >= 0) atomicAdd(&hist[d[u] >> 6], 1);
    __syncthreads();

    for (int i = threadIdx.x; i < nb; i += 256) {
        int h = hist[i];
        hist[i] = (h > 0) ? atomicAdd(&gtail[i], h) : 0;
    }
    __syncthreads();

#pragma unroll
    for (int u = 0; u < 16; u++) {
        if (d[u] >= 0) {
            int b = d[u] >> 6;
            int slot = atomicAdd(&hist[b], 1);
            if (slot < ECAP)
                ebuf[(size_t)b * ECAP + slot] =
                    ((uint)(d[u] & (BN - 1)) << 16) | (uint)s[u];
        }
    }
}

// ---- pass 2: per-bucket LDS scatter -> full-line colbuf + cnt/dinv ----
__global__ __launch_bounds__(256) void k_csr(const uint* __restrict__ ebuf,
                                             const int* __restrict__ gtail,
                                             int n,
                                             ushort* __restrict__ colbuf,
                                             int* __restrict__ cnt,
                                             float* __restrict__ dinv) {
    __shared__ ushort cb[BN * CAP];   // 8KB
    __shared__ int cl[BN];
    int b = blockIdx.x;
    int ne = gtail[b];
    if (ne > ECAP) ne = ECAP;
    for (int i = threadIdx.x; i < BN; i += 256) cl[i] = 0;
    __syncthreads();

    const uint* eb = ebuf + (size_t)b * ECAP;
    for (int i = threadIdx.x * 4; i < ne; i += 1024) {
        uint4 pr4 = *(const uint4*)(eb + i);
        uint prs[4] = {pr4.x, pr4.y, pr4.z, pr4.w};
#pragma unroll
        for (int k = 0; k < 4; k++) {
            if (i + k < ne) {
                int dloc = prs[k] >> 16;
                int p = atomicAdd(&cl[dloc], 1);
                if (p < CAP) cb[dloc * CAP + p] = (ushort)(prs[k] & 0xffffu);
            }
        }
    }
    __syncthreads();

    int node0 = b * BN;
    for (int i = threadIdx.x; i < BN * CAP / 8; i += 256) {
        int node = node0 + i / (CAP / 8);
        if (node < n)
            ((uint4*)&colbuf[(size_t)node0 * CAP])[i] = ((const uint4*)cb)[i];
    }
    for (int i = threadIdx.x; i < BN; i += 256) {
        int node = node0 + i;
        if (node < n) {
            int c = cl[i];
            dinv[node] = rsqrtf((float)c + 1.0f);
            cnt[node] = (c > CAP) ? CAP : c;
        }
    }
}

// ---- MFMA GEMM layer 1: hW1b[n,128](bf16) = X[n,128](f32) @ W1 ----
__global__ __launch_bounds__(256) void k_mgemm1(const float* __restrict__ Xf,
                                                const ushort* __restrict__ Wt,
                                                ushort* __restrict__ Yb, int n) {
    __shared__ ushort Ws[4 * 128 * 32];
    for (int idx = threadIdx.x; idx < 4 * 128 * 32 / 8; idx += 256)
        ((uint4*)Ws)[idx] = ((const uint4*)Wt)[idx];
    __syncthreads();

    int wid  = threadIdx.x >> 6;
    int l    = threadIdx.x & 63;
    int mrow = l & 15;
    int kgrp = l >> 4;
    int row16 = (blockIdx.x * 4 + wid) * 16;
    int r  = row16 + mrow;
    int rc = (r < n) ? r : (n - 1);

    f32x4 acc[8];
#pragma unroll
    for (int t = 0; t < 8; t++) acc[t] = (f32x4){0.f, 0.f, 0.f, 0.f};

#pragma unroll
    for (int kt = 0; kt < 4; kt++) {
        const float* xp = &Xf[(size_t)rc * 128 + kt * 32 + kgrp * 8];
        float4 x0 = *(const float4*)xp;
        float4 x1 = *(const float4*)(xp + 4);
        short8 a;
        a[0] = (short)f2bf(x0.x); a[1] = (short)f2bf(x0.y);
        a[2] = (short)f2bf(x0.z); a[3] = (short)f2bf(x0.w);
        a[4] = (short)f2bf(x1.x); a[5] = (short)f2bf(x1.y);
        a[6] = (short)f2bf(x1.z); a[7] = (short)f2bf(x1.w);
#pragma unroll
        for (int t = 0; t < 8; t++) {
            short8 b = *(const short8*)&Ws[((kt * 128) + t * 16 + mrow) * 32 + kgrp * 8];
            acc[t] = __builtin_amdgcn_mfma_f32_16x16x32_bf16(a, b, acc[t], 0, 0, 0);
        }
    }

    int orow = row16 + kgrp * 4;
#pragma unroll
    for (int t = 0; t < 8; t++) {
#pragma unroll
        for (int q = 0; q < 4; q++) {
            int rr = orow + q;
            if (rr < n) Yb[(size_t)rr * 128 + t * 16 + mrow] = f2bf(acc[t][q]);
        }
    }
}

// ---- MFMA GEMM layer 2: hW2b[n,64](bf16) = x1b[n,128](bf16) @ W2 ----
__global__ __launch_bounds__(256) void k_mgemm2(const ushort* __restrict__ Xh,
                                                const ushort* __restrict__ Wt,
                                                ushort* __restrict__ Yb, int n) {
    __shared__ ushort Ws[4 * 64 * 32];   // 16KB
    for (int idx = threadIdx.x; idx < 4 * 64 * 32 / 8; idx += 256)
        ((uint4*)Ws)[idx] = ((const uint4*)Wt)[idx];
    __syncthreads();

    int wid  = threadIdx.x >> 6;
    int l    = threadIdx.x & 63;
    int mrow = l & 15;
    int kgrp = l >> 4;
    int row16 = (blockIdx.x * 4 + wid) * 16;
    int r  = row16 + mrow;
    int rc = (r < n) ? r : (n - 1);

    f32x4 acc[4];
#pragma unroll
    for (int t = 0; t < 4; t++) acc[t] = (f32x4){0.f, 0.f, 0.f, 0.f};

#pragma unroll
    for (int kt = 0; kt < 4; kt++) {
        short8 a = *(const short8*)&Xh[(size_t)rc * 128 + kt * 32 + kgrp * 8];
#pragma unroll
        for (int t = 0; t < 4; t++) {
            short8 b = *(const short8*)&Ws[((kt * 64) + t * 16 + mrow) * 32 + kgrp * 8];
            acc[t] = __builtin_amdgcn_mfma_f32_16x16x32_bf16(a, b, acc[t], 0, 0, 0);
        }
    }

    int orow = row16 + kgrp * 4;
#pragma unroll
    for (int t = 0; t < 4; t++) {
#pragma unroll
        for (int q = 0; q < 4; q++) {
            int rr = orow + q;
            if (rr < n) Yb[(size_t)rr * 64 + t * 16 + mrow] = f2bf(acc[t][q]);
        }
    }
}

// ---- layer-1 aggregate: x1b = bf16(relu(b1 + di*(sum + di*self))), 16-wide MLP ----
__global__ __launch_bounds__(256) void k_agg1(const ushort* __restrict__ Hb,
                                              const int* __restrict__ cntc,
                                              const ushort* __restrict__ colbuf,
                                              const float* __restrict__ dinv,
                                              const float* __restrict__ b1,
                                              ushort* __restrict__ x1b, int n) {
    const int CH = 128, LPG = 16;
    int t    = blockIdx.x * 256 + threadIdx.x;
    int gid  = t / LPG;
    int lane = t % LPG;
    if (gid >= n) return;

    float di = dinv[gid];
    int c = cntc[gid];
    if (c > CAP) c = CAP;

    // independent loads hoisted: self row + bias
    uint4 aself = *(const uint4*)(Hb + (size_t)gid * CH + lane * 8);
    float4 bb0 = *(const float4*)&b1[lane * 8];
    float4 bb1 = *(const float4*)&b1[lane * 8 + 4];

    float acc[8];
#pragma unroll
    for (int k = 0; k < 8; k++) acc[k] = 0.f;

    const ushort* cb = colbuf + (size_t)gid * CAP;
    for (int j = 0; j < c; j += 16) {
        uint4 iv0 = *(const uint4*)(cb + j);
        uint4 iv1 = *(const uint4*)(cb + j + 8);   // within 128B row (CAP=64) — safe
        uint ivw[8] = {iv0.x, iv0.y, iv0.z, iv0.w, iv1.x, iv1.y, iv1.z, iv1.w};
        int s[16];
#pragma unroll
        for (int u = 0; u < 8; u++) {
            s[2 * u]     = ivw[u] & 0xffff;
            s[2 * u + 1] = ivw[u] >> 16;
        }
#pragma unroll
        for (int u = 1; u < 16; u++) if (j + u >= c) s[u] = s[0];  // s[0] always valid
        float w[16];
#pragma unroll
        for (int u = 0; u < 16; u++)
            w[u] = (j + u < c) ? dinv[s[u]] : 0.f;
        uint4 h[16];
#pragma unroll
        for (int u = 0; u < 16; u++)
            h[u] = *(const uint4*)(Hb + (size_t)s[u] * CH + lane * 8);
#pragma unroll
        for (int u = 0; u < 16; u++) {
            float f0, f1;
            unpackbf2(h[u].x, f0, f1); acc[0] += f0 * w[u]; acc[1] += f1 * w[u];
            unpackbf2(h[u].y, f0, f1); acc[2] += f0 * w[u]; acc[3] += f1 * w[u];
            unpackbf2(h[u].z, f0, f1); acc[4] += f0 * w[u]; acc[5] += f1 * w[u];
            unpackbf2(h[u].w, f0, f1); acc[6] += f0 * w[u]; acc[7] += f1 * w[u];
        }
    }

    float sf[8];
    unpackbf2(aself.x, sf[0], sf[1]);
    unpackbf2(aself.y, sf[2], sf[3]);
    unpackbf2(aself.z, sf[4], sf[5]);
    unpackbf2(aself.w, sf[6], sf[7]);
    float bb[8] = {bb0.x, bb0.y, bb0.z, bb0.w, bb1.x, bb1.y, bb1.z, bb1.w};

    float xv[8];
#pragma unroll
    for (int k = 0; k < 8; k++)
        xv[k] = fmaxf((acc[k] + di * sf[k]) * di + bb[k], 0.f);

    uint up[4] = { packbf2(xv[0], xv[1]), packbf2(xv[2], xv[3]),
                   packbf2(xv[4], xv[5]), packbf2(xv[6], xv[7]) };
    *(uint4*)&x1b[(size_t)gid * CH + lane * 8] = *(uint4*)up;
}

// ---- layer-2 aggregate: out = b2 + di*(sum + di*self), 16-wide MLP ----
__global__ __launch_bounds__(256) void k_agg2(const ushort* __restrict__ Hb,
                                              const int* __restrict__ cntc,
                                              const ushort* __restrict__ colbuf,
                                              const float* __restrict__ dinv,
                                              const float* __restrict__ b2,
                                              float* __restrict__ out, int n) {
    const int CH = 64, LPG = 8;
    int t    = blockIdx.x * 256 + threadIdx.x;
    int gid  = t / LPG;
    int lane = t % LPG;
    if (gid >= n) return;

    float di = dinv[gid];
    int c = cntc[gid];
    if (c > CAP) c = CAP;

    uint4 aself = *(const uint4*)(Hb + (size_t)gid * CH + lane * 8);
    float4 bb0 = *(const float4*)&b2[lane * 8];
    float4 bb1 = *(const float4*)&b2[lane * 8 + 4];

    float acc[8];
#pragma unroll
    for (int k = 0; k < 8; k++) acc[k] = 0.f;

    const ushort* cb = colbuf + (size_t)gid * CAP;
    for (int j = 0; j < c; j += 16) {
        uint4 iv0 = *(const uint4*)(cb + j);
        uint4 iv1 = *(const uint4*)(cb + j + 8);
        uint ivw[8] = {iv0.x, iv0.y, iv0.z, iv0.w, iv1.x, iv1.y, iv1.z, iv1.w};
        int s[16];
#pragma unroll
        for (int u = 0; u < 8; u++) {
            s[2 * u]     = ivw[u] & 0xffff;
            s[2 * u + 1] = ivw[u] >> 16;
        }
#pragma unroll
        for (int u = 1; u < 16; u++) if (j + u >= c) s[u] = s[0];
        float w[16];
#pragma unroll
        for (int u = 0; u < 16; u++)
            w[u] = (j + u < c) ? dinv[s[u]] : 0.f;
        uint4 h[16];
#pragma unroll
        for (int u = 0; u < 16; u++)
            h[u] = *(const uint4*)(Hb + (size_t)s[u] * CH + lane * 8);
#pragma unroll
        for (int u = 0; u < 16; u++) {
            float f0, f1;
            unpackbf2(h[u].x, f0, f1); acc[0] += f0 * w[u]; acc[1] += f1 * w[u];
            unpackbf2(h[u].y, f0, f1); acc[2] += f0 * w[u]; acc[3] += f1 * w[u];
            unpackbf2(h[u].z, f0, f1); acc[4] += f0 * w[u]; acc[5] += f1 * w[u];
            unpackbf2(h[u].w, f0, f1); acc[6] += f0 * w[u]; acc[7] += f1 * w[u];
        }
    }

    float sf[8];
    unpackbf2(aself.x, sf[0], sf[1]);
    unpackbf2(aself.y, sf[2], sf[3]);
    unpackbf2(aself.z, sf[4], sf[5]);
    unpackbf2(aself.w, sf[6], sf[7]);
    float bb[8] = {bb0.x, bb0.y, bb0.z, bb0.w, bb1.x, bb1.y, bb1.z, bb1.w};

    float o[8];
#pragma unroll
    for (int k = 0; k < 8; k++)
        o[k] = (acc[k] + di * sf[k]) * di + bb[k];

    float* dst = out + (size_t)gid * CH + lane * 8;
    *(float4*)dst       = make_float4(o[0], o[1], o[2], o[3]);
    *(float4*)(dst + 4) = make_float4(o[4], o[5], o[6], o[7]);
}

extern "C" void kernel_launch(void* const* d_in, const int* in_sizes, int n_in,
                              void* d_out, int out_size, void* d_ws, size_t ws_size,
                              hipStream_t stream) {
    const float* x  = (const float*)d_in[0];
    const int*   ei = (const int*)d_in[1];
    const float* W1 = (const float*)d_in[2];
    const float* b1 = (const float*)d_in[3];
    const float* W2 = (const float*)d_in[4];
    const float* b2 = (const float*)d_in[5];
    float* out = (float*)d_out;

    int N = in_sizes[0] / 128;
    int E = in_sizes[1] / 2;
    const int* esrc = ei;       // edge_index[0]
    const int* edst = ei + E;   // edge_index[1]

    int nb = (N + BN - 1) / BN;   // 782 buckets

    char* ws = (char*)d_ws;
    size_t off = 0;
    auto alloc = [&](size_t bytes) -> void* {
        off = (off + 255) & ~(size_t)255;
        void* p = ws + off;
        off += bytes;
        return p;
    };
    int*    gtail   = (int*)   alloc((size_t)NBMAX * 4);          // 4KB
    int*    cnt     = (int*)   alloc((size_t)N * 4);
    float*  dinv    = (float*) alloc((size_t)N * 4);
    uint*   ebuf    = (uint*)  alloc((size_t)nb * ECAP * 4);      // 6.4MB
    ushort* colbuf  = (ushort*)alloc((size_t)nb * BN * CAP * 2 + 256);  // 6.4MB
    ushort* hW1b    = (ushort*)alloc((size_t)N * 128 * 2);        // 12.8MB
    ushort* x1b     = (ushort*)alloc((size_t)N * 128 * 2);        // 12.8MB
    ushort* hW2b    = (ushort*)alloc((size_t)N * 64 * 2);         // 6.4MB
    ushort* W1t     = (ushort*)alloc((size_t)4 * 128 * 32 * 2);   // 32KB
    ushort* W2t     = (ushort*)alloc((size_t)4 * 64 * 32 * 2);    // 16KB

    k_init<<<96, 256, 0, stream>>>(W1, W2, W1t, W2t, gtail);

    int nbP1 = (E + P1E - 1) / P1E;
    k_part<<<nbP1, 256, 0, stream>>>(esrc, edst, E, nb, gtail, ebuf);
    k_mgemm1<<<(N + 63) / 64, 256, 0, stream>>>(x, W1t, hW1b, N);
    k_csr<<<nb, 256, 0, stream>>>(ebuf, gtail, N, colbuf, cnt, dinv);

    k_agg1<<<((size_t)N * 16 + 255) / 256, 256, 0, stream>>>(
        hW1b, cnt, colbuf, dinv, b1, x1b, N);

    k_mgemm2<<<(N + 63) / 64, 256, 0, stream>>>(x1b, W2t, hW2b, N);

    k_agg2<<<((size_t)N * 8 + 255) / 256, 256, 0, stream>>>(
        hW2b, cnt, colbuf, dinv, b2, out, N);
}